// Round 9
// baseline (65.091 us; speedup 1.0000x reference)
//
#include <hip/hip_runtime.h>

#define VIEWN 360
#define NDETC 736
#define HWPIX 102400     // 320*320
#define VC    8          // view chunks in backprojection
#define VPC   45         // views per chunk
#define NWORK 66240      // 360*184 conv output-workers (4 outputs each)
#define FBLK  518        // conv blocks: ceil(66240/128)

// ws layout (bytes)
#define OFF_FILT 0                         // 360*736 f32   = 1,059,840
#define OFF_PART 1059840                   // 8*102400 f32  = 3,276,800
#define OFF_DTAB 4336640                   // 4*360 f64     = 11,520
#define OFF_FTAB 4348160                   // 4*360 f32     = 5,760
#define OFF_IY   4353920                   // 360 i32

// ---------------------------------------------------------------------------
// Kernel 1: blocks 0..517 — ramp-filter conv; block 518 — per-view tables.
// g is ANALYTIC (== Re(ifft(recon_filter)), verified identical to the DFT g):
//   g[m] = 0.25*(h[m] + h[(2048-m)&2047]),  h[idx]: n=idx-735,
//   h = 1 at n=0, -4/(pi^2 n^2) at odd n, else 0   (DELTA_S=0.5 folded)
// filt[v][d] = sum_k sino[v][k]*cw[k]*g[d+735-k]; 4 outputs/worker, k-range
// split across 2 thread-halves, combined in LDS (value-rounding only).
// FMA mapping (window: c = gs[d+732-k0 .. d+735-k0], p = gs[d+736 .. d+739-k0]):
//   out d+m, tap kk needs gs[d+m+735-k0-kk] — verified per-line below.
// ---------------------------------------------------------------------------
__global__ __launch_bounds__(256) void filter_tab_kernel(
    const float* __restrict__ sino, const float* __restrict__ cw,
    const float* __restrict__ grid, char* __restrict__ ws)
{
    const int tid = threadIdx.x;
    if (blockIdx.x == FBLK) {
        double* dtab = (double*)(ws + OFF_DTAB);
        float*  ftab = (float*) (ws + OFF_FTAB);
        int*    iyt  = (int*)   (ws + OFF_IY);
        for (int v = tid; v < VIEWN; v += 256) {
            const double db   = ((3.141592653589793 * 360.0) / 360.0) / 180.0;
            const double stop = 359.0 * db;           // np.linspace replication
            const double step = stop / 359.0;
            const double beta = (v == 359) ? stop : (double)v * step;
            const double sb = sin(beta), cb = cos(beta);
            const double CGX = 500.0 / 183.75;        // SCD / s_range[-1]
            dtab[4*v] = sb; dtab[4*v+1] = cb; dtab[4*v+2] = cb*CGX; dtab[4*v+3] = sb*CGX;
            ftab[4*v] = (float)sb; ftab[4*v+1] = (float)cb;
            ftab[4*v+2] = (float)(cb*CGX); ftab[4*v+3] = (float)(sb*CGX);
            const float gy = grid[(size_t)v * HWPIX * 2 + 1];  // tiled per view
            float t = __fadd_rn(gy, 1.f);             // strict f32 == numpy
            t = __fmul_rn(t, 360.f);
            t = __fadd_rn(t, -1.f);
            t = __fmul_rn(t, 0.5f);
            iyt[v] = __float2int_rn(t);               // v=359 -> 360 -> invalid
        }
        return;
    }
    __shared__ __align__(16) float gs[1472];
    __shared__ __align__(16) float ws2[2][NDETC];
    __shared__ __align__(16) float comb[128][4];
    float* filt = (float*)(ws + OFF_FILT);
    const int b = blockIdx.x;
    const int vbase = (b * 128) / 184;
    for (int m = tid; m < 1472; m += 256) {           // analytic ramp kernel
        const int n1 = m - 735;
        const int n2 = ((2048 - m) & 2047) - 735;
        const double h1 = (n1 == 0) ? 1.0 : ((n1 & 1) ? -4.0 / (9.869604401089358 * (double)(n1 * n1)) : 0.0);
        const double h2 = (n2 == 0) ? 1.0 : ((n2 & 1) ? -4.0 / (9.869604401089358 * (double)(n2 * n2)) : 0.0);
        gs[m] = (float)(0.25 * (h1 + h2));
    }
    for (int idx = tid; idx < 2 * NDETC; idx += 256) { // stage <=2 sino rows
        const int vv = idx / NDETC, k = idx % NDETC;
        const int v = vbase + vv;
        if (v < VIEWN) ws2[vv][k] = sino[v * NDETC + k] * cw[k];
    }
    __syncthreads();
    const int o    = b * 128 + (tid & 127);           // output-worker id
    const int half = tid >> 7;                        // k-range half
    float4 acc = make_float4(0.f, 0.f, 0.f, 0.f);
    int v = 0, d = 0;
    if (o < NWORK) {
        v = o / 184;
        d = 4 * (o % 184);
        const float* wsrow = ws2[v - vbase];
        const int kbeg = 368 * half;
        float4 p = *(const float4*)&gs[d + 736 - kbeg];   // win[4..6] seed
        for (int k0 = kbeg; k0 < kbeg + 368; k0 += 4) {
            const float4 c = *(const float4*)&gs[d + 732 - k0]; // 16B-aligned
            const float4 w = *(const float4*)&wsrow[k0];
            // kk=0: gs[d+735-k0+m] -> c.w, p.x, p.y, p.z
            acc.x = fmaf(w.x, c.w, acc.x);
            acc.y = fmaf(w.x, p.x, acc.y);
            acc.z = fmaf(w.x, p.y, acc.z);
            acc.w = fmaf(w.x, p.z, acc.w);
            // kk=1: gs[d+734-k0+m] -> c.z, c.w, p.x, p.y
            acc.x = fmaf(w.y, c.z, acc.x);
            acc.y = fmaf(w.y, c.w, acc.y);
            acc.z = fmaf(w.y, p.x, acc.z);
            acc.w = fmaf(w.y, p.y, acc.w);
            // kk=2: gs[d+733-k0+m] -> c.y, c.z, c.w, p.x
            acc.x = fmaf(w.z, c.y, acc.x);
            acc.y = fmaf(w.z, c.z, acc.y);   // FIXED: addend acc.y (was acc.z in r8)
            acc.z = fmaf(w.z, c.w, acc.z);
            acc.w = fmaf(w.z, p.x, acc.w);
            // kk=3: gs[d+732-k0+m] -> c.x, c.y, c.z, c.w
            acc.x = fmaf(w.w, c.x, acc.x);
            acc.y = fmaf(w.w, c.y, acc.y);
            acc.z = fmaf(w.w, c.z, acc.z);
            acc.w = fmaf(w.w, c.w, acc.w);
            p = c;
        }
    }
    if (half == 1) *(float4*)&comb[tid & 127][0] = acc;
    __syncthreads();
    if (half == 0 && o < NWORK) {
        const float4 bs = *(const float4*)&comb[tid][0];
        acc.x += bs.x; acc.y += bs.y; acc.z += bs.z; acc.w += bs.w;
        *(float4*)&filt[v * NDETC + d] = acc;          // 16B-aligned
    }
}

// ---------------------------------------------------------------------------
// Kernel 2: backprojection, f32 fast path + f64 wave-redo near half-integers.
// Fast path tx error <= ~2.8e-4; guard window 1e-3 (3.6x margin); redo waves
// (~12%) recompute gx in f64 (rcpf + 2 Newton) — decisions then match the
// host's f64->f32 cast chain. Rounds 5/6 bit-identical failures showed the
// fast path is decision-identical to f64 on this data.
// ---------------------------------------------------------------------------
__global__ __launch_bounds__(256) void bp_kernel(
    char* __restrict__ ws, float* __restrict__ part_out)
{
    const float*  filt = (const float*)(ws + OFF_FILT);
    const double* dtab = (const double*)(ws + OFF_DTAB);
    const float*  ftab = (const float*)(ws + OFF_FTAB);
    const int*    iyt  = (const int*)(ws + OFF_IY);
    const int pb = blockIdx.x, c = blockIdx.y;
    const int p  = pb * 256 + threadIdx.x;
    const int j  = p % 320, i = p / 320;
    const float  xjf = ((float)j - 159.5f) * 1.1f;
    const float  yif = ((float)i - 159.5f) * 1.1f;
    const double xj  = ((double)j - 159.5) * 1.1;   // exact f64 grid coords
    const double yi  = ((double)i - 159.5) * 1.1;
    float acc = 0.f;
    const int v0 = c * VPC;
    #pragma unroll 5
    for (int v = v0; v < v0 + VPC; ++v) {
        const int iy = iyt[v];                        // uniform scalar
        if ((unsigned)iy >= 360u) continue;           // v=359: all invalid
        const float sbf = ftab[4*v], cbf = ftab[4*v+1];
        const float cbCf = ftab[4*v+2], sbCf = ftab[4*v+3];
        const float t = fmaf(sbf, xjf, fmaf(-cbf, yif, 500.f)); // 500*U
        const float r = __builtin_amdgcn_rcpf(t);     // 1/t, ~1ulp
        const float numC = fmaf(cbCf, xjf, sbCf * yif);
        float tx = __fadd_rn(numC * r, 1.f);          // strict f32 chain
        tx = __fmul_rn(tx, 736.f);
        tx = __fadd_rn(tx, -1.f);
        tx = __fmul_rn(tx, 0.5f);
        const float dd = fabsf(tx - rintf(tx));
        if (__any(dd > 0.499f)) {                     // near half-int: f64 redo
            const double sb = dtab[4*v], cb = dtab[4*v+1];
            const double cbC = dtab[4*v+2], sbC = dtab[4*v+3];
            const double td = fma(sb, xj, 500.0 - cb * yi);
            double r0 = (double)__builtin_amdgcn_rcpf((float)td);
            r0 = r0 * fma(-td, r0, 2.0);              // Newton 1
            r0 = r0 * fma(-td, r0, 2.0);              // Newton 2: ~f64 rounding
            const double gxd = fma(cbC, xj, sbC * yi) * r0;
            float txx = __fadd_rn((float)gxd, 1.f);
            txx = __fmul_rn(txx, 736.f);
            txx = __fadd_rn(txx, -1.f);
            txx = __fmul_rn(txx, 0.5f);
            tx = txx;
        }
        const int ix = __float2int_rn(tx);            // round half-to-even
        const float w = 250000.f * r * r;             // 1/U^2, ~3e-7 rel
        const float val = ((unsigned)ix < 736u) ? filt[iy * NDETC + ix] : 0.f;
        acc = fmaf(val, w, acc);
    }
    part_out[(size_t)c * HWPIX + p] = acc;
}

// ---------------------------------------------------------------------------
// Kernel 3: out[p] = D_BETA * sum_c part[c][p] * mask[p]  (c-ascending order)
// Separate launch: the kernel boundary guarantees cross-XCD visibility.
// ---------------------------------------------------------------------------
__global__ __launch_bounds__(256) void reduce_kernel(
    const float* __restrict__ part, const float* __restrict__ mask,
    float* __restrict__ out)
{
    const int p = blockIdx.x * 256 + threadIdx.x;
    const double db = ((3.141592653589793 * 360.0) / 360.0) / 180.0;
    float s = 0.f;
    #pragma unroll
    for (int cc = 0; cc < VC; ++cc)
        s += part[(size_t)cc * HWPIX + p];
    out[p] = (float)(db * (double)s * (double)mask[p]);
}

extern "C" void kernel_launch(void* const* d_in, const int* in_sizes, int n_in,
                              void* d_out, int out_size, void* d_ws, size_t ws_size,
                              hipStream_t stream)
{
    (void)in_sizes; (void)n_in; (void)out_size; (void)ws_size;
    const float* sino = (const float*)d_in[0];
    const float* cw   = (const float*)d_in[1];
    const float* grid = (const float*)d_in[4];
    const float* mask = (const float*)d_in[6];
    float* out = (float*)d_out;
    char*  ws  = (char*)d_ws;
    float* part = (float*)(ws + OFF_PART);

    filter_tab_kernel<<<FBLK + 1, 256, 0, stream>>>(sino, cw, grid, ws);
    bp_kernel<<<dim3(HWPIX / 256, VC), 256, 0, stream>>>(ws, part);
    reduce_kernel<<<HWPIX / 256, 256, 0, stream>>>(part, mask, out);
}